// Round 12
// baseline (212.388 us; speedup 1.0000x reference)
//
#include <hip/hip_runtime.h>
#include <hip/hip_bf16.h>
#include <hip/hip_fp16.h>

#define NQ_   8192
#define DM_   256
#define NH_   6
#define DH_   64
#define BATCH 2

typedef __attribute__((ext_vector_type(8))) short short8;
typedef __attribute__((ext_vector_type(4))) short short4v;
typedef __attribute__((ext_vector_type(4))) float float4v;
typedef __attribute__((ext_vector_type(2))) float f32x2;
typedef __attribute__((ext_vector_type(4))) unsigned int uint32x4;
typedef __attribute__((ext_vector_type(4))) int int32x4;

#if defined(__has_builtin)
#if __has_builtin(__builtin_amdgcn_make_buffer_rsrc) && __has_builtin(__builtin_amdgcn_raw_ptr_buffer_load_b128)
#define USE_BUFLD 1
#endif
#endif
#ifndef USE_BUFLD
#define USE_BUFLD 0
#endif

// ---------------- workspace layout ----------------
// vws f16 [2*6][10080][64] = 15,482,880 B   (f16: feeds v_fma_mix_f32 directly)
static const size_t VOFF_L0 = 0;
static const size_t VOFF_L1 = 5898240;
static const size_t VOFF_L2 = 7372800;
static const size_t QRAW_BYTE_OFF  = 15482880;   // qraw f32 [16384][486]
static const size_t MID_BYTE_OFF   = 47333376;   // mid bf16 [16384][384]
static const size_t QBF_BYTE_OFF   = 47333376;   // qbf bf16 [16384][256] — aliases mid (lifetimes disjoint)
static const size_t WT_BYTE_OFF    = 59916288;
static const size_t FEATT_BYTE_OFF = 60558336;   // fT bf16 -> end 70,880,256
static const size_t REF_BYTE_OFF   = 70880256;   // float [16384][3][2] = 393,216 B -> end 71,273,472
// wT element offsets
static const size_t WVT_OFF   = 0;        // 384 rows x 256
static const size_t WOFFT_OFF = 98304;    // 324 rows x 256 (query path may over-read to row 511 — stays inside wT)
static const size_t WATTN_OFF = 181248;   // 162 rows x 256
static const size_t WOUTT_OFF = 222720;   // 256 rows x 384
// featT element offsets
static const size_t FT_L0 = 0;
static const size_t FT_L1 = 3932160;
static const size_t FT_L2 = 4915200;

__device__ __forceinline__ unsigned short f2bf(float f) {
    unsigned int u = __float_as_uint(f);
    unsigned int r = (u + 0x7fffu + ((u >> 16) & 1u)) >> 16;
    return (unsigned short)r;
}

// async global->LDS, 16B per lane; LDS dest must be wave-uniform base + lane*16
__device__ __forceinline__ void cp16(void* lds, const void* g) {
    __builtin_amdgcn_global_load_lds(
        (const __attribute__((address_space(1))) unsigned int*)g,
        (__attribute__((address_space(3))) unsigned int*)lds, 16, 0, 0);
}

// f32 += f32(w) * f16(lo/hi of d); f32 accumulate — no unpack instructions
__device__ __forceinline__ void fm_lo(float& acc, float w, unsigned d) {
    asm("v_fma_mix_f32 %0, %1, %2, %0 op_sel:[0,0,0] op_sel_hi:[0,1,0]"
        : "+v"(acc) : "v"(w), "v"(d));
}
__device__ __forceinline__ void fm_hi(float& acc, float w, unsigned d) {
    asm("v_fma_mix_f32 %0, %1, %2, %0 op_sel:[0,1,0] op_sel_hi:[0,1,0]"
        : "+v"(acc) : "v"(w), "v"(d));
}

// ============ prep_all ============
// weights T tiled 64x64 (0..83) | feat T (84..2603) | qbf (2604..3627) | ref (3628..3691)
__global__ __launch_bounds__(256) void prep_all(const float* __restrict__ Wv,
                                                const float* __restrict__ Woff,
                                                const float* __restrict__ Wattn,
                                                const float* __restrict__ Wout,
                                                const float* __restrict__ feat0,
                                                const float* __restrict__ feat1,
                                                const float* __restrict__ feat2,
                                                const float* __restrict__ x,
                                                const float* __restrict__ pe,
                                                const float* __restrict__ coor,
                                                const float* __restrict__ cam2img,
                                                const float* __restrict__ l2c,
                                                unsigned short* __restrict__ wT,
                                                unsigned short* __restrict__ fT,
                                                unsigned short* __restrict__ qbf,
                                                float* __restrict__ ref) {
    const int pid = blockIdx.x, t = threadIdx.x;
    if (pid < 84) {
        // weight transpose, LDS-tiled 64(n) x 64(k): coalesced load over n, coalesced store over k
        __shared__ float tile[64][65];
        int r = pid;
        const float* src; int K, N, nt, kt; size_t base;
        if (r < 24)      { src = Wv;    K = 256; N = 384; nt = r >> 2; kt = r & 3; base = WVT_OFF; }
        else if (r < 48) { r -= 24; src = Woff;  K = 256; N = 324; nt = r >> 2; kt = r & 3; base = WOFFT_OFF; }
        else if (r < 60) { r -= 48; src = Wattn; K = 256; N = 162; nt = r >> 2; kt = r & 3; base = WATTN_OFF; }
        else             { r -= 60; src = Wout;  K = 384; N = 256; nt = r / 6;  kt = r % 6; base = WOUTT_OFF; }
        const int n0 = nt * 64, k0t = kt * 64;
        {
            int nl = t & 63, kl4 = t >> 6;                 // load: lanes sweep n (coalesced)
            int nn = min(n0 + nl, N - 1);
#pragma unroll
            for (int i = 0; i < 16; ++i) {
                int kl = kl4 + i * 4;
                tile[nl][kl] = src[(size_t)(k0t + kl) * N + nn];
            }
        }
        __syncthreads();
        {
            int kl = t & 63, nl4 = t >> 6;                 // store: lanes sweep k (coalesced)
#pragma unroll
            for (int i = 0; i < 16; ++i) {
                int nl = nl4 + i * 4;
                if (n0 + nl < N)
                    wT[base + (size_t)(n0 + nl) * K + k0t + kl] = f2bf(tile[nl][kl]);
            }
        }
        return;
    }
    if (pid < 2604) {
        // feat transpose: 64c x 32p tile; reads 128B-coalesced, writes 128B-coalesced
        __shared__ float tile[64][33];
        int f = pid - 84;
        const float* src; unsigned short* dst; int HW;
        if (f < 1920)      { src = feat0; dst = fT + FT_L0; HW = 7680; }
        else if (f < 2400) { src = feat1; dst = fT + FT_L1; HW = 1920; f -= 1920; }
        else               { src = feat2; dst = fT + FT_L2; HW = 480;  f -= 2400; }
        int pb = f >> 3, rem = f & 7, cb = rem >> 1, b = rem & 1;
        int p0 = pb * 32, c0 = cb * 64;
        {
            int px = t & 31, cy = t >> 5;          // cy 0..7
#pragma unroll
            for (int i = 0; i < 8; ++i) {
                int cr = cy + i * 8;
                tile[cr][px] = src[((size_t)(b * DM_ + c0 + cr)) * HW + p0 + px];
            }
        }
        __syncthreads();
        {
            int cx = t & 63, py = t >> 6;          // py 0..3
#pragma unroll
            for (int i = 0; i < 8; ++i) {
                int pr = py + i * 4;
                dst[((size_t)b * HW + p0 + pr) * DM_ + c0 + cx] = f2bf(tile[cx][pr]);
            }
        }
        return;
    }
    if (pid < 3628) {
        // qbf: 1024 blocks, 4096 elements each
        int f = pid - 2604;
#pragma unroll
        for (int i = 0; i < 4; ++i) {
            size_t e = (size_t)f * 4096 + i * 1024 + t * 4;
            float4 xv = *(const float4*)&x[e];
            float4 pv = *(const float4*)&pe[e];
            short4v o;
            o[0] = (short)f2bf(xv.x + pv.x);
            o[1] = (short)f2bf(xv.y + pv.y);
            o[2] = (short)f2bf(xv.z + pv.z);
            o[3] = (short)f2bf(xv.w + pv.w);
            *(short4v*)&qbf[e] = o;
        }
        return;
    }
    // ref precompute: 64 blocks x 256 = 16384 queries; stores (ref_l - 0.5) per level as float2
    {
        int q = (pid - 3628) * 256 + t;
        int b = q >> 13;
        float c0 = coor[(size_t)q * 3 + 0];
        float c1 = coor[(size_t)q * 3 + 1];
        float c2 = coor[(size_t)q * 3 + 2];
        const float* L = l2c + b * 16;
        const float* C = cam2img + b * 16;
        float pc0 = L[0] * c0 + L[1] * c1 + L[2]  * c2 + L[3];
        float pc1 = L[4] * c0 + L[5] * c1 + L[6]  * c2 + L[7];
        float pc2 = L[8] * c0 + L[9] * c1 + L[10] * c2 + L[11];
        float q0 = C[0] * pc0 + C[1] * pc1 + C[2]  * pc2 + C[3];
        float q1 = C[4] * pc0 + C[5] * pc1 + C[6]  * pc2 + C[7];
        float q2 = C[8] * pc0 + C[9] * pc1 + C[10] * pc2 + C[11];
        float rz = __frcp_rn(q2);
        float rx = q0 * rz * 0.125f, ry = q1 * rz * 0.125f;   // level-0 units
#pragma unroll
        for (int l = 0; l < 3; ++l) {
            float sl = (l == 0) ? 1.f : ((l == 1) ? 0.5f : 0.25f);
            f32x2 v = {rx * sl - 0.5f, ry * sl - 0.5f};
            *(f32x2*)&ref[(size_t)q * 6 + l * 2] = v;
        }
    }
}

// ============ MFMA inner block, BK=64, XOR-swizzled [rows][64] LDS ============
// LDS slot (r, s) holds logical col s ^ ((r&7)*8); read logical q at q ^ ((r&7)*8).
__device__ __forceinline__ void mfma_block64(const short A[][64], const short B[][64],
                                             int wm, int wn, int lane, float4v acc[4][4]) {
    int mb = wm + (lane & 15);
    int nb = wn + (lane & 15);
    int q8 = (lane >> 4) * 8;
#pragma unroll
    for (int kk = 0; kk < 2; ++kk) {
        short8 af[4], bf[4];
#pragma unroll
        for (int i = 0; i < 4; ++i) {
            int m = mb + i * 16;
            af[i] = *(const short8*)&A[m][(q8 + kk * 32) ^ ((m & 7) * 8)];
        }
#pragma unroll
        for (int j = 0; j < 4; ++j) {
            int n = nb + j * 16;
            bf[j] = *(const short8*)&B[n][(q8 + kk * 32) ^ ((n & 7) * 8)];
        }
#pragma unroll
        for (int i = 0; i < 4; ++i)
#pragma unroll
            for (int j = 0; j < 4; ++j)
                acc[i][j] = __builtin_amdgcn_mfma_f32_16x16x32_bf16(af[i], bf[j], acc[i][j], 0, 0, 0);
    }
}

// ============ fused value GEMM (blocks 0..473) + query GEMM (blocks 474..985) ============
// BK=64: 4 K-steps (8 barriers vs 16); LDS 32 KB; source-preswizzled staging (linear LDS dest).
__global__ __launch_bounds__(256) void gemm_vq(const unsigned short* __restrict__ fT,
                                               const unsigned short* __restrict__ wT,
                                               const float* __restrict__ bv,
                                               unsigned short* __restrict__ vws,
                                               const unsigned short* __restrict__ qbf,
                                               const float* __restrict__ boff,
                                               const float* __restrict__ battn,
                                               float* __restrict__ qraw) {
    __shared__ short A[128][64];
    __shared__ short B[128][64];
    const int tid = threadIdx.x;
    const int lane = tid & 63, wave = tid >> 6;
    const int wm = (wave & 1) * 64, wn = (wave >> 1) * 64;
    const int id = blockIdx.x;
    const int sr = tid >> 3;                       // 0..31 (staging row base)
    const int sc8 = (tid & 7) * 8;                 // LDS col (linear dest)
    const int scsw = (((tid & 7) ^ (sr & 7)) * 8); // pre-swizzled GLOBAL col
    float4v acc[4][4];
#pragma unroll
    for (int i = 0; i < 4; ++i)
#pragma unroll
        for (int j = 0; j < 4; ++j) acc[i][j] = (float4v){0.f, 0.f, 0.f, 0.f};

    if (id < 474) {
        // ---- value path ----
        int pb = id / 6, rem = id % 6;
        int nb = rem >> 1, b = rem & 1;
        int pbl, HW; size_t ftoff, voff;
        if (pb < 60)      { pbl = pb;      HW = 7680; ftoff = FT_L0; voff = VOFF_L0; }
        else if (pb < 75) { pbl = pb - 60; HW = 1920; ftoff = FT_L1; voff = VOFF_L1; }
        else              { pbl = pb - 75; HW = 480;  ftoff = FT_L2; voff = VOFF_L2; }
        const int p0 = pbl * 128, n0 = nb * 128;
        const unsigned short* Asrc = fT + ftoff + (size_t)b * HW * DM_;
        const unsigned short* wvT = wT + WVT_OFF;
        int prow[4];
#pragma unroll
        for (int i = 0; i < 4; ++i) { int p = p0 + sr + 32 * i; prow[i] = min(p, HW - 1); }

        for (int k0 = 0; k0 < DM_; k0 += 64) {
#pragma unroll
            for (int i = 0; i < 4; ++i)
                cp16(&A[sr + 32 * i][sc8], &Asrc[(size_t)prow[i] * DM_ + k0 + scsw]);
#pragma unroll
            for (int i = 0; i < 4; ++i)
                cp16(&B[sr + 32 * i][sc8], &wvT[(size_t)(n0 + sr + 32 * i) * DM_ + k0 + scsw]);
            __syncthreads();
            mfma_block64(A, B, wm, wn, lane, acc);
            __syncthreads();
        }
        int colb = n0 + wn + (lane & 15);
        int rowq = (lane >> 4) * 4;
#pragma unroll
        for (int i = 0; i < 4; ++i)
#pragma unroll
            for (int j = 0; j < 4; ++j) {
                int n = colb + j * 16;
                int h = n >> 6, d = n & 63;
                float bias = bv[n];
#pragma unroll
                for (int r = 0; r < 4; ++r) {
                    int p = p0 + wm + i * 16 + rowq + r;
                    if (p < HW)
                        vws[voff + ((size_t)(b * NH_ + h) * HW + p) * DH_ + d] =
                            __half_as_ushort(__float2half(acc[i][j][r] + bias));
                }
            }
    } else {
        // ---- query path (bf16 staging from qbf) ----
        int qid = id - 474;
        const int m0 = (qid & 127) * 128, n0 = (qid >> 7) * 128;
        const unsigned short* wq = wT + WOFFT_OFF;   // rows up to 511 stay inside wT allocation

        for (int k0 = 0; k0 < DM_; k0 += 64) {
#pragma unroll
            for (int i = 0; i < 4; ++i)
                cp16(&A[sr + 32 * i][sc8], &qbf[(size_t)(m0 + sr + 32 * i) * DM_ + k0 + scsw]);
#pragma unroll
            for (int i = 0; i < 4; ++i)
                cp16(&B[sr + 32 * i][sc8], &wq[(size_t)(n0 + sr + 32 * i) * DM_ + k0 + scsw]);
            __syncthreads();
            mfma_block64(A, B, wm, wn, lane, acc);
            __syncthreads();
        }
        int colb = n0 + wn + (lane & 15);
        int rowq = (lane >> 4) * 4;
#pragma unroll
        for (int i = 0; i < 4; ++i)
#pragma unroll
            for (int j = 0; j < 4; ++j) {
                int n = colb + j * 16;
                if (n < 486) {
                    float bias = (n < 324) ? boff[n] : battn[n - 324];
#pragma unroll
                    for (int r = 0; r < 4; ++r) {
                        int m = m0 + wm + i * 16 + rowq + r;
                        qraw[(size_t)m * 486 + n] = acc[i][j][r] + bias;
                    }
                }
            }
    }
}

// ---- gather batch helper: f16 data, v_fma_mix accumulate (no unpack ops) ----
template<int N>
__device__ __forceinline__ void gather_batch(const int2* __restrict__ pl, int t0, unsigned cb,
#if USE_BUFLD
                                             __amdgpu_buffer_rsrc_t vrs,
#else
                                             const char* vbase,
#endif
                                             float (&a)[8]) {
    int2 pw[N];
    uint32x4 d[N];
#pragma unroll
    for (int t = 0; t < N; ++t) pw[t] = pl[t0 + t];
#pragma unroll
    for (int t = 0; t < N; ++t) {
#if USE_BUFLD
        int32x4 t4 = __builtin_amdgcn_raw_ptr_buffer_load_b128(
            vrs, (int)((unsigned)pw[t].x + cb), 0, 0);
        d[t] = __builtin_bit_cast(uint32x4, t4);
#else
        d[t] = *(const uint32x4*)(vbase + ((unsigned)pw[t].x + cb));
#endif
    }
#pragma unroll
    for (int t = 0; t < N; ++t) {
        float w = __int_as_float(pw[t].y);
        fm_lo(a[0], w, d[t][0]); fm_hi(a[1], w, d[t][0]);
        fm_lo(a[2], w, d[t][1]); fm_hi(a[3], w, d[t][1]);
        fm_lo(a[4], w, d[t][2]); fm_hi(a[5], w, d[t][2]);
        fm_lo(a[6], w, d[t][3]); fm_hi(a[7], w, d[t][3]);
    }
}

// ============ fused softmax + gather: 8 queries per block, query-level pipeline ============
// 192 threads = 3 waves; wave w owns heads {2w, 2w+1} in BOTH phases, so s_plan is WAVE-PRIVATE:
// no __syncthreads at all — waves run as independent 8-query pipelines (per-wave trip variance
// no longer re-syncs). Next query's plan loads (logit/oxy/ref) are issued right after the current
// plan scatter, so their ~600cy latency drains under the current gather (T14 at query granularity).
// Grid 2048 = 8 blocks/CU: whole grid co-resident.
// launch_bounds(192,6): known-good; VGPR ~28 incl. preload regs. Spill guard: WRITE_SIZE = 12,288 KB.
__global__ __launch_bounds__(192, 6) void sample_kernel(const float* __restrict__ qraw,
                                                        const float* __restrict__ ref,
                                                        const unsigned short* __restrict__ vws,
                                                        unsigned short* __restrict__ mid) {
    __shared__ int2 s_plan[792];     // [(c*6+h)*33 + slot]; group stride 33 staggers banks
    const int tid = threadIdx.x;
    const int h = tid >> 5, j = tid & 31;
    const bool act = j < 27;
    const int l = (j >= 18) ? 2 : ((j >= 9) ? 1 : 0);   // lane-static level
    const int corner = j >> 3;
    const unsigned cb = (unsigned)((j & 7) << 4);       // 16B chunk of the 128B pixel row
    const int2* pl = &s_plan[(corner * 6 + h) * 33];

#if USE_BUFLD
    __amdgpu_buffer_rsrc_t vrs = __builtin_amdgcn_make_buffer_rsrc(
        const_cast<unsigned short*>(vws), (short)0, 15482880, 0x00020000);
#define VARG vrs
#else
    const char* vbase = (const char*)vws;
#define VARG vbase
#endif

    int bq = blockIdx.x * 8;
    // preload query 0's plan inputs
    float plog = act ? qraw[(size_t)bq * 486 + 324 + h * 27 + j] : -1e30f;
    float2 poxy = make_float2(0.f, 0.f);
    f32x2 pr2 = {0.f, 0.f};
    if (act) {
        poxy = *(const float2*)&qraw[(size_t)bq * 486 + h * 54 + j * 2];
        pr2  = *(const f32x2*)&ref[(size_t)bq * 6 + l * 2];
    }

    for (int it = 0; it < 8; ++it, ++bq) {
        const int b = bq >> 13;
        const float logit = plog;
        const float2 oxy = poxy;
        const f32x2 r2 = pr2;

        float m = logit;
#pragma unroll
        for (int msk = 16; msk >= 1; msk >>= 1) m = fmaxf(m, __shfl_xor(m, msk, 32));
        float e = act ? __expf(logit - m) : 0.f;
        float ssum = e;
#pragma unroll
        for (int msk = 16; msk >= 1; msk >>= 1) ssum += __shfl_xor(ssum, msk, 32);

        bool keep = false;
        int off0 = 0, off1 = 0;
        float p00 = 0.f, p01 = 0.f, p10 = 0.f, p11 = 0.f;
        if (act) {
            float attn = e * __frcp_rn(ssum);
            int wl = 160 >> l, hl = 48 >> l;
            int HWl = (l == 0) ? 7680 : ((l == 1) ? 1920 : 480);
            int lvlb = (l == 0) ? 0 : ((l == 1) ? 11796480 : 14745600);
            float X = r2[0] + oxy.x;
            float Y = r2[1] + oxy.y;
            float x0f = floorf(X), y0f = floorf(Y);
            float fx = X - x0f, fy = Y - y0f;
            int ix = (int)x0f, iy = (int)y0f;
            int bx = min(max(ix, 0), wl - 2);
            float wx0 = ((bx == ix) ? (1.f - fx) : 0.f) + ((bx == ix + 1) ? fx : 0.f);
            float wx1 = ((bx + 1 == ix) ? (1.f - fx) : 0.f) + ((bx + 1 == ix + 1) ? fx : 0.f);
            int cy0 = min(max(iy, 0), hl - 1);
            int cy1 = min(max(iy + 1, 0), hl - 1);
            float wy0 = (iy >= 0 && iy < hl) ? (1.f - fy) : 0.f;
            float wy1 = (iy + 1 >= 0 && iy + 1 < hl) ? fy : 0.f;
            keep = ((wy0 + wy1) * (wx0 + wx1)) != 0.f;
            int slice = (b * NH_ + h) * HWl;
            off0 = lvlb + (slice + cy0 * wl + bx) * 128;
            off1 = lvlb + (slice + cy1 * wl + bx) * 128;
            p00 = attn * wy0 * wx0;
            p01 = attn * wy0 * wx1;
            p10 = attn * wy1 * wx0;
            p11 = attn * wy1 * wx1;
        }
        unsigned long long mask = __ballot(keep);
        unsigned lo32 = (unsigned)mask, hi32 = (unsigned)(mask >> 32);
        bool upper = (tid & 32) != 0;
        unsigned gmask = upper ? hi32 : lo32;   // this lane-half's head
        unsigned omask = upper ? lo32 : hi32;   // sibling head in the same wave
        int slot = __popc(gmask & ((1u << j) - 1));
        int cn = __popc(gmask);
        int ntq = max(cn, __popc(omask));
        ntq = ((ntq + 2) / 3) * 3;              // multiple of 3, 0..27
        if (keep) {
            s_plan[(0 * 6 + h) * 33 + slot] = make_int2(off0,       __float_as_int(p00));
            s_plan[(1 * 6 + h) * 33 + slot] = make_int2(off0 + 128, __float_as_int(p01));
            s_plan[(2 * 6 + h) * 33 + slot] = make_int2(off1,       __float_as_int(p10));
            s_plan[(3 * 6 + h) * 33 + slot] = make_int2(off1 + 128, __float_as_int(p11));
        }
        // pad this head's list up to the wave trip (wave-private)
        if (j >= cn && j < ntq) {
            int2 z = make_int2(0, 0);
            s_plan[(0 * 6 + h) * 33 + j] = z;
            s_plan[(1 * 6 + h) * 33 + j] = z;
            s_plan[(2 * 6 + h) * 33 + j] = z;
            s_plan[(3 * 6 + h) * 33 + j] = z;
        }

        // issue NEXT query's plan loads now — latency hides under the gather below
        if (it < 7) {
            int bqn = bq + 1;
            plog = act ? qraw[(size_t)bqn * 486 + 324 + h * 27 + j] : -1e30f;
            if (act) {
                poxy = *(const float2*)&qraw[(size_t)bqn * 486 + h * 54 + j * 2];
                pr2  = *(const f32x2*)&ref[(size_t)bqn * 6 + l * 2];
            }
        }

        float a[8] = {0.f, 0.f, 0.f, 0.f, 0.f, 0.f, 0.f, 0.f};
        int t0 = 0;
        for (; t0 + 9 <= ntq; t0 += 9) gather_batch<9>(pl, t0, cb, VARG, a);
        for (; t0 < ntq; t0 += 3)      gather_batch<3>(pl, t0, cb, VARG, a);

#pragma unroll
        for (int i = 0; i < 8; ++i) {
            a[i] += __shfl_xor(a[i], 8, 64);
            a[i] += __shfl_xor(a[i], 16, 64);
        }
        if (corner == 0) {
            uint4 pk;
            pk.x = (unsigned)f2bf(a[0]) | ((unsigned)f2bf(a[1]) << 16);
            pk.y = (unsigned)f2bf(a[2]) | ((unsigned)f2bf(a[3]) << 16);
            pk.z = (unsigned)f2bf(a[4]) | ((unsigned)f2bf(a[5]) << 16);
            pk.w = (unsigned)f2bf(a[6]) | ((unsigned)f2bf(a[7]) << 16);
            *(uint4*)&mid[(size_t)bq * 384 + h * DH_ + ((j & 7) << 3)] = pk;
        }
        // no barrier: s_plan groups are wave-private (same h in plan and gather phases)
    }
}

// ============ out GEMM: 64x128 tiles, BK=64 (6 K-steps), swizzled LDS ============
__global__ __launch_bounds__(256) void out_gemm(const unsigned short* __restrict__ mid,
                                                const unsigned short* __restrict__ woT,
                                                const float* __restrict__ bout,
                                                float* __restrict__ out) {
    __shared__ short A[64][64];
    __shared__ short B[128][64];
    const int tid = threadIdx.x;
    const int m0 = blockIdx.x * 64, n0 = blockIdx.y * 128;
    const int lane = tid & 63, wave = tid >> 6;
    const int wn = wave * 32;
    const int sr = tid >> 3;
    const int sc8 = (tid & 7) * 8;
    const int scsw = (((tid & 7) ^ (sr & 7)) * 8);
    float4v acc[4][2];
#pragma unroll
    for (int i = 0; i < 4; ++i)
#pragma unroll
        for (int j = 0; j < 2; ++j) acc[i][j] = (float4v){0.f, 0.f, 0.f, 0.f};

    for (int k0 = 0; k0 < 384; k0 += 64) {
#pragma unroll
        for (int i = 0; i < 2; ++i)
            cp16(&A[sr + 32 * i][sc8], &mid[(size_t)(m0 + sr + 32 * i) * 384 + k0 + scsw]);
#pragma unroll
        for (int i = 0; i < 4; ++i)
            cp16(&B[sr + 32 * i][sc8], &woT[(size_t)(n0 + sr + 32 * i) * 384 + k0 + scsw]);
        __syncthreads();
        {
            int mb = lane & 15;
            int nb = wn + (lane & 15);
            int q8 = (lane >> 4) * 8;
#pragma unroll
            for (int kk = 0; kk < 2; ++kk) {
                short8 af[4], bf[2];
#pragma unroll
                for (int i = 0; i < 4; ++i) {
                    int m = mb + i * 16;
                    af[i] = *(const short8*)&A[m][(q8 + kk * 32) ^ ((m & 7) * 8)];
                }
#pragma unroll
                for (int j = 0; j < 2; ++j) {
                    int n = nb + j * 16;
                    bf[j] = *(const short8*)&B[n][(q8 + kk * 32) ^ ((n & 7) * 8)];
                }
#pragma unroll
                for (int i = 0; i < 4; ++i)
#pragma unroll
                    for (int j = 0; j < 2; ++j)
                        acc[i][j] = __builtin_amdgcn_mfma_f32_16x16x32_bf16(af[i], bf[j], acc[i][j], 0, 0, 0);
            }
        }
        __syncthreads();
    }
    int colb = n0 + wn + (lane & 15);
    int rowq = (lane >> 4) * 4;
#pragma unroll
    for (int i = 0; i < 4; ++i)
#pragma unroll
        for (int j = 0; j < 2; ++j) {
            int n = colb + j * 16;
            float bias = bout[n];
#pragma unroll
            for (int r = 0; r < 4; ++r) {
                int m = m0 + i * 16 + rowq + r;
                out[(size_t)m * 256 + n] = acc[i][j][r] + bias;
            }
        }
}

extern "C" void kernel_launch(void* const* d_in, const int* in_sizes, int n_in,
                              void* d_out, int out_size, void* d_ws, size_t ws_size,
                              hipStream_t stream) {
    const float* x      = (const float*)d_in[0];
    const float* pe     = (const float*)d_in[1];
    const float* coor   = (const float*)d_in[2];
    const float* c2i    = (const float*)d_in[3];
    const float* l2c    = (const float*)d_in[4];
    const float* feat0  = (const float*)d_in[5];
    const float* feat1  = (const float*)d_in[6];
    const float* feat2  = (const float*)d_in[7];
    const float* Wv     = (const float*)d_in[8];
    const float* bv     = (const float*)d_in[9];
    const float* Woff   = (const float*)d_in[10];
    const float* boff   = (const float*)d_in[11];
    const float* Wattn  = (const float*)d_in[12];
    const float* battn  = (const float*)d_in[13];
    const float* Wout   = (const float*)d_in[14];
    const float* bout   = (const float*)d_in[15];

    unsigned short* vws = (unsigned short*)d_ws;
    float* qraw         = (float*)((char*)d_ws + QRAW_BYTE_OFF);
    unsigned short* mid = (unsigned short*)((char*)d_ws + MID_BYTE_OFF);
    unsigned short* qbf = (unsigned short*)((char*)d_ws + QBF_BYTE_OFF);
    unsigned short* wT  = (unsigned short*)((char*)d_ws + WT_BYTE_OFF);
    unsigned short* fT  = (unsigned short*)((char*)d_ws + FEATT_BYTE_OFF);
    float* ref          = (float*)((char*)d_ws + REF_BYTE_OFF);
    float* out          = (float*)d_out;

    prep_all<<<dim3(3692), 256, 0, stream>>>(Wv, Woff, Wattn, Wout, feat0, feat1, feat2,
                                             x, pe, coor, c2i, l2c, wT, fT, qbf, ref);
    gemm_vq<<<dim3(986), 256, 0, stream>>>(fT, wT, bv, vws, qbf, boff, battn, qraw);
    sample_kernel<<<dim3(BATCH * NQ_ / 8), 192, 0, stream>>>(qraw, ref, vws, mid);
    out_gemm<<<dim3(256, 2), 256, 0, stream>>>(mid, wT + WOUTT_OFF, bout, out);
}

// Round 13
// 201.812 us; speedup vs baseline: 1.0524x; 1.0524x over previous
//
#include <hip/hip_runtime.h>
#include <hip/hip_bf16.h>
#include <hip/hip_fp16.h>

#define NQ_   8192
#define DM_   256
#define NH_   6
#define DH_   64
#define BATCH 2

typedef __attribute__((ext_vector_type(8))) short short8;
typedef __attribute__((ext_vector_type(4))) short short4v;
typedef __attribute__((ext_vector_type(4))) float float4v;
typedef __attribute__((ext_vector_type(2))) float f32x2;
typedef __attribute__((ext_vector_type(4))) unsigned int uint32x4;
typedef __attribute__((ext_vector_type(4))) int int32x4;

#if defined(__has_builtin)
#if __has_builtin(__builtin_amdgcn_make_buffer_rsrc) && __has_builtin(__builtin_amdgcn_raw_ptr_buffer_load_b128)
#define USE_BUFLD 1
#endif
#endif
#ifndef USE_BUFLD
#define USE_BUFLD 0
#endif

// ---------------- workspace layout ----------------
// vws f16 [2*6][10080][64] = 15,482,880 B   (f16: feeds v_fma_mix_f32 directly)
static const size_t VOFF_L0 = 0;
static const size_t VOFF_L1 = 5898240;
static const size_t VOFF_L2 = 7372800;
static const size_t QRAW_BYTE_OFF  = 15482880;   // qraw f32 [16384][486]
static const size_t MID_BYTE_OFF   = 47333376;   // mid bf16 [16384][384]
static const size_t QBF_BYTE_OFF   = 47333376;   // qbf bf16 [16384][256] — aliases mid (lifetimes disjoint)
static const size_t WT_BYTE_OFF    = 59916288;
static const size_t FEATT_BYTE_OFF = 60558336;   // fT bf16 -> end 70,880,256
static const size_t REF_BYTE_OFF   = 70880256;   // float [16384][3][2] = 393,216 B -> end 71,273,472
// wT element offsets
static const size_t WVT_OFF   = 0;        // 384 rows x 256
static const size_t WOFFT_OFF = 98304;    // 324 rows x 256 (query path may over-read to row 511 — stays inside wT)
static const size_t WATTN_OFF = 181248;   // 162 rows x 256
static const size_t WOUTT_OFF = 222720;   // 256 rows x 384
// featT element offsets
static const size_t FT_L0 = 0;
static const size_t FT_L1 = 3932160;
static const size_t FT_L2 = 4915200;

__device__ __forceinline__ unsigned short f2bf(float f) {
    unsigned int u = __float_as_uint(f);
    unsigned int r = (u + 0x7fffu + ((u >> 16) & 1u)) >> 16;
    return (unsigned short)r;
}

// async global->LDS, 16B per lane; LDS dest must be wave-uniform base + lane*16
__device__ __forceinline__ void cp16(void* lds, const void* g) {
    __builtin_amdgcn_global_load_lds(
        (const __attribute__((address_space(1))) unsigned int*)g,
        (__attribute__((address_space(3))) unsigned int*)lds, 16, 0, 0);
}

// f32 += f32(w) * f16(lo/hi of d); f32 accumulate — no unpack instructions
__device__ __forceinline__ void fm_lo(float& acc, float w, unsigned d) {
    asm("v_fma_mix_f32 %0, %1, %2, %0 op_sel:[0,0,0] op_sel_hi:[0,1,0]"
        : "+v"(acc) : "v"(w), "v"(d));
}
__device__ __forceinline__ void fm_hi(float& acc, float w, unsigned d) {
    asm("v_fma_mix_f32 %0, %1, %2, %0 op_sel:[0,1,0] op_sel_hi:[0,1,0]"
        : "+v"(acc) : "v"(w), "v"(d));
}

// ============ prep_all ============
// weights T tiled 64x64 (0..83) | feat T (84..2603) | qbf (2604..3627) | ref (3628..3691)
__global__ __launch_bounds__(256) void prep_all(const float* __restrict__ Wv,
                                                const float* __restrict__ Woff,
                                                const float* __restrict__ Wattn,
                                                const float* __restrict__ Wout,
                                                const float* __restrict__ feat0,
                                                const float* __restrict__ feat1,
                                                const float* __restrict__ feat2,
                                                const float* __restrict__ x,
                                                const float* __restrict__ pe,
                                                const float* __restrict__ coor,
                                                const float* __restrict__ cam2img,
                                                const float* __restrict__ l2c,
                                                unsigned short* __restrict__ wT,
                                                unsigned short* __restrict__ fT,
                                                unsigned short* __restrict__ qbf,
                                                float* __restrict__ ref) {
    const int pid = blockIdx.x, t = threadIdx.x;
    if (pid < 84) {
        // weight transpose, LDS-tiled 64(n) x 64(k): coalesced load over n, coalesced store over k
        __shared__ float tile[64][65];
        int r = pid;
        const float* src; int K, N, nt, kt; size_t base;
        if (r < 24)      { src = Wv;    K = 256; N = 384; nt = r >> 2; kt = r & 3; base = WVT_OFF; }
        else if (r < 48) { r -= 24; src = Woff;  K = 256; N = 324; nt = r >> 2; kt = r & 3; base = WOFFT_OFF; }
        else if (r < 60) { r -= 48; src = Wattn; K = 256; N = 162; nt = r >> 2; kt = r & 3; base = WATTN_OFF; }
        else             { r -= 60; src = Wout;  K = 384; N = 256; nt = r / 6;  kt = r % 6; base = WOUTT_OFF; }
        const int n0 = nt * 64, k0t = kt * 64;
        {
            int nl = t & 63, kl4 = t >> 6;                 // load: lanes sweep n (coalesced)
            int nn = min(n0 + nl, N - 1);
#pragma unroll
            for (int i = 0; i < 16; ++i) {
                int kl = kl4 + i * 4;
                tile[nl][kl] = src[(size_t)(k0t + kl) * N + nn];
            }
        }
        __syncthreads();
        {
            int kl = t & 63, nl4 = t >> 6;                 // store: lanes sweep k (coalesced)
#pragma unroll
            for (int i = 0; i < 16; ++i) {
                int nl = nl4 + i * 4;
                if (n0 + nl < N)
                    wT[base + (size_t)(n0 + nl) * K + k0t + kl] = f2bf(tile[nl][kl]);
            }
        }
        return;
    }
    if (pid < 2604) {
        // feat transpose: 64c x 32p tile; reads 128B-coalesced, writes 128B-coalesced
        __shared__ float tile[64][33];
        int f = pid - 84;
        const float* src; unsigned short* dst; int HW;
        if (f < 1920)      { src = feat0; dst = fT + FT_L0; HW = 7680; }
        else if (f < 2400) { src = feat1; dst = fT + FT_L1; HW = 1920; f -= 1920; }
        else               { src = feat2; dst = fT + FT_L2; HW = 480;  f -= 2400; }
        int pb = f >> 3, rem = f & 7, cb = rem >> 1, b = rem & 1;
        int p0 = pb * 32, c0 = cb * 64;
        {
            int px = t & 31, cy = t >> 5;          // cy 0..7
#pragma unroll
            for (int i = 0; i < 8; ++i) {
                int cr = cy + i * 8;
                tile[cr][px] = src[((size_t)(b * DM_ + c0 + cr)) * HW + p0 + px];
            }
        }
        __syncthreads();
        {
            int cx = t & 63, py = t >> 6;          // py 0..3
#pragma unroll
            for (int i = 0; i < 8; ++i) {
                int pr = py + i * 4;
                dst[((size_t)b * HW + p0 + pr) * DM_ + c0 + cx] = f2bf(tile[cx][pr]);
            }
        }
        return;
    }
    if (pid < 3628) {
        // qbf: 1024 blocks, 4096 elements each
        int f = pid - 2604;
#pragma unroll
        for (int i = 0; i < 4; ++i) {
            size_t e = (size_t)f * 4096 + i * 1024 + t * 4;
            float4 xv = *(const float4*)&x[e];
            float4 pv = *(const float4*)&pe[e];
            short4v o;
            o[0] = (short)f2bf(xv.x + pv.x);
            o[1] = (short)f2bf(xv.y + pv.y);
            o[2] = (short)f2bf(xv.z + pv.z);
            o[3] = (short)f2bf(xv.w + pv.w);
            *(short4v*)&qbf[e] = o;
        }
        return;
    }
    // ref precompute: 64 blocks x 256 = 16384 queries; stores (ref_l - 0.5) per level as float2
    {
        int q = (pid - 3628) * 256 + t;
        int b = q >> 13;
        float c0 = coor[(size_t)q * 3 + 0];
        float c1 = coor[(size_t)q * 3 + 1];
        float c2 = coor[(size_t)q * 3 + 2];
        const float* L = l2c + b * 16;
        const float* C = cam2img + b * 16;
        float pc0 = L[0] * c0 + L[1] * c1 + L[2]  * c2 + L[3];
        float pc1 = L[4] * c0 + L[5] * c1 + L[6]  * c2 + L[7];
        float pc2 = L[8] * c0 + L[9] * c1 + L[10] * c2 + L[11];
        float q0 = C[0] * pc0 + C[1] * pc1 + C[2]  * pc2 + C[3];
        float q1 = C[4] * pc0 + C[5] * pc1 + C[6]  * pc2 + C[7];
        float q2 = C[8] * pc0 + C[9] * pc1 + C[10] * pc2 + C[11];
        float rz = __frcp_rn(q2);
        float rx = q0 * rz * 0.125f, ry = q1 * rz * 0.125f;   // level-0 units
#pragma unroll
        for (int l = 0; l < 3; ++l) {
            float sl = (l == 0) ? 1.f : ((l == 1) ? 0.5f : 0.25f);
            f32x2 v = {rx * sl - 0.5f, ry * sl - 0.5f};
            *(f32x2*)&ref[(size_t)q * 6 + l * 2] = v;
        }
    }
}

// ============ MFMA inner block, BK=64, XOR-swizzled [rows][64] LDS ============
// LDS slot (r, s) holds logical col s ^ ((r&7)*8); read logical q at q ^ ((r&7)*8).
__device__ __forceinline__ void mfma_block64(const short A[][64], const short B[][64],
                                             int wm, int wn, int lane, float4v acc[4][4]) {
    int mb = wm + (lane & 15);
    int nb = wn + (lane & 15);
    int q8 = (lane >> 4) * 8;
#pragma unroll
    for (int kk = 0; kk < 2; ++kk) {
        short8 af[4], bf[4];
#pragma unroll
        for (int i = 0; i < 4; ++i) {
            int m = mb + i * 16;
            af[i] = *(const short8*)&A[m][(q8 + kk * 32) ^ ((m & 7) * 8)];
        }
#pragma unroll
        for (int j = 0; j < 4; ++j) {
            int n = nb + j * 16;
            bf[j] = *(const short8*)&B[n][(q8 + kk * 32) ^ ((n & 7) * 8)];
        }
#pragma unroll
        for (int i = 0; i < 4; ++i)
#pragma unroll
            for (int j = 0; j < 4; ++j)
                acc[i][j] = __builtin_amdgcn_mfma_f32_16x16x32_bf16(af[i], bf[j], acc[i][j], 0, 0, 0);
    }
}

// ============ fused value GEMM (blocks 0..473) + query GEMM (blocks 474..985) ============
// BK=64: 4 K-steps (8 barriers vs 16); LDS 32 KB; source-preswizzled staging (linear LDS dest).
__global__ __launch_bounds__(256) void gemm_vq(const unsigned short* __restrict__ fT,
                                               const unsigned short* __restrict__ wT,
                                               const float* __restrict__ bv,
                                               unsigned short* __restrict__ vws,
                                               const unsigned short* __restrict__ qbf,
                                               const float* __restrict__ boff,
                                               const float* __restrict__ battn,
                                               float* __restrict__ qraw) {
    __shared__ short A[128][64];
    __shared__ short B[128][64];
    const int tid = threadIdx.x;
    const int lane = tid & 63, wave = tid >> 6;
    const int wm = (wave & 1) * 64, wn = (wave >> 1) * 64;
    const int id = blockIdx.x;
    const int sr = tid >> 3;                       // 0..31 (staging row base)
    const int sc8 = (tid & 7) * 8;                 // LDS col (linear dest)
    const int scsw = (((tid & 7) ^ (sr & 7)) * 8); // pre-swizzled GLOBAL col
    float4v acc[4][4];
#pragma unroll
    for (int i = 0; i < 4; ++i)
#pragma unroll
        for (int j = 0; j < 4; ++j) acc[i][j] = (float4v){0.f, 0.f, 0.f, 0.f};

    if (id < 474) {
        // ---- value path ----
        int pb = id / 6, rem = id % 6;
        int nb = rem >> 1, b = rem & 1;
        int pbl, HW; size_t ftoff, voff;
        if (pb < 60)      { pbl = pb;      HW = 7680; ftoff = FT_L0; voff = VOFF_L0; }
        else if (pb < 75) { pbl = pb - 60; HW = 1920; ftoff = FT_L1; voff = VOFF_L1; }
        else              { pbl = pb - 75; HW = 480;  ftoff = FT_L2; voff = VOFF_L2; }
        const int p0 = pbl * 128, n0 = nb * 128;
        const unsigned short* Asrc = fT + ftoff + (size_t)b * HW * DM_;
        const unsigned short* wvT = wT + WVT_OFF;
        int prow[4];
#pragma unroll
        for (int i = 0; i < 4; ++i) { int p = p0 + sr + 32 * i; prow[i] = min(p, HW - 1); }

        for (int k0 = 0; k0 < DM_; k0 += 64) {
#pragma unroll
            for (int i = 0; i < 4; ++i)
                cp16(&A[sr + 32 * i][sc8], &Asrc[(size_t)prow[i] * DM_ + k0 + scsw]);
#pragma unroll
            for (int i = 0; i < 4; ++i)
                cp16(&B[sr + 32 * i][sc8], &wvT[(size_t)(n0 + sr + 32 * i) * DM_ + k0 + scsw]);
            __syncthreads();
            mfma_block64(A, B, wm, wn, lane, acc);
            __syncthreads();
        }
        int colb = n0 + wn + (lane & 15);
        int rowq = (lane >> 4) * 4;
#pragma unroll
        for (int i = 0; i < 4; ++i)
#pragma unroll
            for (int j = 0; j < 4; ++j) {
                int n = colb + j * 16;
                int h = n >> 6, d = n & 63;
                float bias = bv[n];
#pragma unroll
                for (int r = 0; r < 4; ++r) {
                    int p = p0 + wm + i * 16 + rowq + r;
                    if (p < HW)
                        vws[voff + ((size_t)(b * NH_ + h) * HW + p) * DH_ + d] =
                            __half_as_ushort(__float2half(acc[i][j][r] + bias));
                }
            }
    } else {
        // ---- query path (bf16 staging from qbf) ----
        int qid = id - 474;
        const int m0 = (qid & 127) * 128, n0 = (qid >> 7) * 128;
        const unsigned short* wq = wT + WOFFT_OFF;   // rows up to 511 stay inside wT allocation

        for (int k0 = 0; k0 < DM_; k0 += 64) {
#pragma unroll
            for (int i = 0; i < 4; ++i)
                cp16(&A[sr + 32 * i][sc8], &qbf[(size_t)(m0 + sr + 32 * i) * DM_ + k0 + scsw]);
#pragma unroll
            for (int i = 0; i < 4; ++i)
                cp16(&B[sr + 32 * i][sc8], &wq[(size_t)(n0 + sr + 32 * i) * DM_ + k0 + scsw]);
            __syncthreads();
            mfma_block64(A, B, wm, wn, lane, acc);
            __syncthreads();
        }
        int colb = n0 + wn + (lane & 15);
        int rowq = (lane >> 4) * 4;
#pragma unroll
        for (int i = 0; i < 4; ++i)
#pragma unroll
            for (int j = 0; j < 4; ++j) {
                int n = colb + j * 16;
                if (n < 486) {
                    float bias = (n < 324) ? boff[n] : battn[n - 324];
#pragma unroll
                    for (int r = 0; r < 4; ++r) {
                        int m = m0 + wm + i * 16 + rowq + r;
                        qraw[(size_t)m * 486 + n] = acc[i][j][r] + bias;
                    }
                }
            }
    }
}

// ---- gather batch helper: f16 data, v_fma_mix accumulate (no unpack ops) ----
template<int N>
__device__ __forceinline__ void gather_batch(const int2* __restrict__ pl, int t0, unsigned cb,
#if USE_BUFLD
                                             __amdgpu_buffer_rsrc_t vrs,
#else
                                             const char* vbase,
#endif
                                             float (&a)[8]) {
    int2 pw[N];
    uint32x4 d[N];
#pragma unroll
    for (int t = 0; t < N; ++t) pw[t] = pl[t0 + t];
#pragma unroll
    for (int t = 0; t < N; ++t) {
#if USE_BUFLD
        int32x4 t4 = __builtin_amdgcn_raw_ptr_buffer_load_b128(
            vrs, (int)((unsigned)pw[t].x + cb), 0, 0);
        d[t] = __builtin_bit_cast(uint32x4, t4);
#else
        d[t] = *(const uint32x4*)(vbase + ((unsigned)pw[t].x + cb));
#endif
    }
#pragma unroll
    for (int t = 0; t < N; ++t) {
        float w = __int_as_float(pw[t].y);
        fm_lo(a[0], w, d[t][0]); fm_hi(a[1], w, d[t][0]);
        fm_lo(a[2], w, d[t][1]); fm_hi(a[3], w, d[t][1]);
        fm_lo(a[4], w, d[t][2]); fm_hi(a[5], w, d[t][2]);
        fm_lo(a[6], w, d[t][3]); fm_hi(a[7], w, d[t][3]);
    }
}

// ============ fused softmax + gather: ONE query per block, per-head tap compaction ============
// 192 threads = 3 waves. Wave w owns heads {2w, 2w+1}; slots via ballot/popc; per-wave trip ntq.
// REVERTED to the round-10 structure (best measured: sample 56.0-56.4 us, total 202.6):
// one query per block, grid 16384 — block-level TLP is the latency-hiding mechanism here.
// R11 (occupancy hint) was null; R12 (8-query in-block pipeline) was -10 us (FETCH +29 MB,
// VALUBusy 66->47): do NOT re-attempt in-block pipelining.
// launch_bounds(192,6): VGPR 20. Spill guard: WRITE_SIZE must stay 12,288 KB.
__global__ __launch_bounds__(192, 6) void sample_kernel(const float* __restrict__ qraw,
                                                        const float* __restrict__ ref,
                                                        const unsigned short* __restrict__ vws,
                                                        unsigned short* __restrict__ mid) {
    __shared__ int2 s_plan[792];     // [(c*6+h)*33 + slot], slot < 33; group stride 33 staggers banks
    const int tid = threadIdx.x;
    const int bq = blockIdx.x;
    const int b = bq >> 13;
    int ntq;                          // per-wave trip count (register, survives the barrier)

    {
        int h = tid >> 5, j = tid & 31;
        bool act = j < 27;
        float logit = act ? qraw[(size_t)bq * 486 + 324 + h * 27 + j] : -1e30f;
        float m = logit;
#pragma unroll
        for (int msk = 16; msk >= 1; msk >>= 1) m = fmaxf(m, __shfl_xor(m, msk, 32));
        float e = act ? __expf(logit - m) : 0.f;
        float ssum = e;
#pragma unroll
        for (int msk = 16; msk >= 1; msk >>= 1) ssum += __shfl_xor(ssum, msk, 32);

        bool keep = false;
        int off0 = 0, off1 = 0;
        float p00 = 0.f, p01 = 0.f, p10 = 0.f, p11 = 0.f;
        if (act) {
            float attn = e * __frcp_rn(ssum);
            int l = (j >= 18) ? 2 : ((j >= 9) ? 1 : 0);
            int wl = 160 >> l, hl = 48 >> l;
            int HWl = (l == 0) ? 7680 : ((l == 1) ? 1920 : 480);
            int lvlb = (l == 0) ? 0 : ((l == 1) ? 11796480 : 14745600);
            f32x2 r2 = *(const f32x2*)&ref[(size_t)bq * 6 + l * 2];
            float2 oxy = *(const float2*)&qraw[(size_t)bq * 486 + h * 54 + j * 2];
            float X = r2[0] + oxy.x;
            float Y = r2[1] + oxy.y;
            float x0f = floorf(X), y0f = floorf(Y);
            float fx = X - x0f, fy = Y - y0f;
            int ix = (int)x0f, iy = (int)y0f;
            int bx = min(max(ix, 0), wl - 2);
            float wx0 = ((bx == ix) ? (1.f - fx) : 0.f) + ((bx == ix + 1) ? fx : 0.f);
            float wx1 = ((bx + 1 == ix) ? (1.f - fx) : 0.f) + ((bx + 1 == ix + 1) ? fx : 0.f);
            int cy0 = min(max(iy, 0), hl - 1);
            int cy1 = min(max(iy + 1, 0), hl - 1);
            float wy0 = (iy >= 0 && iy < hl) ? (1.f - fy) : 0.f;
            float wy1 = (iy + 1 >= 0 && iy + 1 < hl) ? fy : 0.f;
            keep = ((wy0 + wy1) * (wx0 + wx1)) != 0.f;
            int slice = (b * NH_ + h) * HWl;
            off0 = lvlb + (slice + cy0 * wl + bx) * 128;
            off1 = lvlb + (slice + cy1 * wl + bx) * 128;
            p00 = attn * wy0 * wx0;
            p01 = attn * wy0 * wx1;
            p10 = attn * wy1 * wx0;
            p11 = attn * wy1 * wx1;
        }
        unsigned long long mask = __ballot(keep);
        unsigned lo32 = (unsigned)mask, hi32 = (unsigned)(mask >> 32);
        bool upper = (tid & 32) != 0;
        unsigned gmask = upper ? hi32 : lo32;   // this lane-half's head
        unsigned omask = upper ? lo32 : hi32;   // sibling head in the same wave
        int slot = __popc(gmask & ((1u << j) - 1));
        int cn = __popc(gmask);
        ntq = max(cn, __popc(omask));
        ntq = ((ntq + 2) / 3) * 3;              // multiple of 3, 0..27
        if (keep) {
            s_plan[(0 * 6 + h) * 33 + slot] = make_int2(off0,       __float_as_int(p00));
            s_plan[(1 * 6 + h) * 33 + slot] = make_int2(off0 + 128, __float_as_int(p01));
            s_plan[(2 * 6 + h) * 33 + slot] = make_int2(off1,       __float_as_int(p10));
            s_plan[(3 * 6 + h) * 33 + slot] = make_int2(off1 + 128, __float_as_int(p11));
        }
        // pad this head's list up to the wave trip (wave-private)
        if (j >= cn && j < ntq) {
            int2 z = make_int2(0, 0);
            s_plan[(0 * 6 + h) * 33 + j] = z;
            s_plan[(1 * 6 + h) * 33 + j] = z;
            s_plan[(2 * 6 + h) * 33 + j] = z;
            s_plan[(3 * 6 + h) * 33 + j] = z;
        }
    }
    __syncthreads();

    const int h = tid >> 5;
    const int l32 = tid & 31;
    const int corner = l32 >> 3;
    const unsigned cb = (unsigned)((l32 & 7) << 4);   // 16B chunk of the 128B pixel row
    const int2* pl = &s_plan[(corner * 6 + h) * 33];
    float a[8] = {0.f, 0.f, 0.f, 0.f, 0.f, 0.f, 0.f, 0.f};

#if USE_BUFLD
    __amdgpu_buffer_rsrc_t vrs = __builtin_amdgcn_make_buffer_rsrc(
        const_cast<unsigned short*>(vws), (short)0, 15482880, 0x00020000);
#define VARG vrs
#else
    const char* vbase = (const char*)vws;
#define VARG vbase
#endif

    int t0 = 0;
    for (; t0 + 9 <= ntq; t0 += 9) gather_batch<9>(pl, t0, cb, VARG, a);
    for (; t0 < ntq; t0 += 3)      gather_batch<3>(pl, t0, cb, VARG, a);

#pragma unroll
    for (int i = 0; i < 8; ++i) {
        a[i] += __shfl_xor(a[i], 8, 64);
        a[i] += __shfl_xor(a[i], 16, 64);
    }
    if (corner == 0) {
        uint4 pk;
        pk.x = (unsigned)f2bf(a[0]) | ((unsigned)f2bf(a[1]) << 16);
        pk.y = (unsigned)f2bf(a[2]) | ((unsigned)f2bf(a[3]) << 16);
        pk.z = (unsigned)f2bf(a[4]) | ((unsigned)f2bf(a[5]) << 16);
        pk.w = (unsigned)f2bf(a[6]) | ((unsigned)f2bf(a[7]) << 16);
        *(uint4*)&mid[(size_t)bq * 384 + h * DH_ + ((l32 & 7) << 3)] = pk;
    }
}

// ============ out GEMM: 64x128 tiles, BK=64 (6 K-steps), swizzled LDS ============
__global__ __launch_bounds__(256) void out_gemm(const unsigned short* __restrict__ mid,
                                                const unsigned short* __restrict__ woT,
                                                const float* __restrict__ bout,
                                                float* __restrict__ out) {
    __shared__ short A[64][64];
    __shared__ short B[128][64];
    const int tid = threadIdx.x;
    const int m0 = blockIdx.x * 64, n0 = blockIdx.y * 128;
    const int lane = tid & 63, wave = tid >> 6;
    const int wn = wave * 32;
    const int sr = tid >> 3;
    const int sc8 = (tid & 7) * 8;
    const int scsw = (((tid & 7) ^ (sr & 7)) * 8);
    float4v acc[4][2];
#pragma unroll
    for (int i = 0; i < 4; ++i)
#pragma unroll
        for (int j = 0; j < 2; ++j) acc[i][j] = (float4v){0.f, 0.f, 0.f, 0.f};

    for (int k0 = 0; k0 < 384; k0 += 64) {
#pragma unroll
        for (int i = 0; i < 2; ++i)
            cp16(&A[sr + 32 * i][sc8], &mid[(size_t)(m0 + sr + 32 * i) * 384 + k0 + scsw]);
#pragma unroll
        for (int i = 0; i < 4; ++i)
            cp16(&B[sr + 32 * i][sc8], &woT[(size_t)(n0 + sr + 32 * i) * 384 + k0 + scsw]);
        __syncthreads();
        {
            int mb = lane & 15;
            int nb = wn + (lane & 15);
            int q8 = (lane >> 4) * 8;
#pragma unroll
            for (int kk = 0; kk < 2; ++kk) {
                short8 af[4], bf[2];
#pragma unroll
                for (int i = 0; i < 4; ++i) {
                    int m = mb + i * 16;
                    af[i] = *(const short8*)&A[m][(q8 + kk * 32) ^ ((m & 7) * 8)];
                }
#pragma unroll
                for (int j = 0; j < 2; ++j) {
                    int n = nb + j * 16;
                    bf[j] = *(const short8*)&B[n][(q8 + kk * 32) ^ ((n & 7) * 8)];
                }
#pragma unroll
                for (int i = 0; i < 4; ++i)
#pragma unroll
                    for (int j = 0; j < 2; ++j)
                        acc[i][j] = __builtin_amdgcn_mfma_f32_16x16x32_bf16(af[i], bf[j], acc[i][j], 0, 0, 0);
            }
        }
        __syncthreads();
    }
    int colb = n0 + wn + (lane & 15);
    int rowq = (lane >> 4) * 4;
#pragma unroll
    for (int i = 0; i < 4; ++i)
#pragma unroll
        for (int j = 0; j < 2; ++j) {
            int n = colb + j * 16;
            float bias = bout[n];
#pragma unroll
            for (int r = 0; r < 4; ++r) {
                int m = m0 + i * 16 + rowq + r;
                out[(size_t)m * 256 + n] = acc[i][j][r] + bias;
            }
        }
}

extern "C" void kernel_launch(void* const* d_in, const int* in_sizes, int n_in,
                              void* d_out, int out_size, void* d_ws, size_t ws_size,
                              hipStream_t stream) {
    const float* x      = (const float*)d_in[0];
    const float* pe     = (const float*)d_in[1];
    const float* coor   = (const float*)d_in[2];
    const float* c2i    = (const float*)d_in[3];
    const float* l2c    = (const float*)d_in[4];
    const float* feat0  = (const float*)d_in[5];
    const float* feat1  = (const float*)d_in[6];
    const float* feat2  = (const float*)d_in[7];
    const float* Wv     = (const float*)d_in[8];
    const float* bv     = (const float*)d_in[9];
    const float* Woff   = (const float*)d_in[10];
    const float* boff   = (const float*)d_in[11];
    const float* Wattn  = (const float*)d_in[12];
    const float* battn  = (const float*)d_in[13];
    const float* Wout   = (const float*)d_in[14];
    const float* bout   = (const float*)d_in[15];

    unsigned short* vws = (unsigned short*)d_ws;
    float* qraw         = (float*)((char*)d_ws + QRAW_BYTE_OFF);
    unsigned short* mid = (unsigned short*)((char*)d_ws + MID_BYTE_OFF);
    unsigned short* qbf = (unsigned short*)((char*)d_ws + QBF_BYTE_OFF);
    unsigned short* wT  = (unsigned short*)((char*)d_ws + WT_BYTE_OFF);
    unsigned short* fT  = (unsigned short*)((char*)d_ws + FEATT_BYTE_OFF);
    float* ref          = (float*)((char*)d_ws + REF_BYTE_OFF);
    float* out          = (float*)d_out;

    prep_all<<<dim3(3692), 256, 0, stream>>>(Wv, Woff, Wattn, Wout, feat0, feat1, feat2,
                                             x, pe, coor, c2i, l2c, wT, fT, qbf, ref);
    gemm_vq<<<dim3(986), 256, 0, stream>>>(fT, wT, bv, vws, qbf, boff, battn, qraw);
    sample_kernel<<<dim3(BATCH * NQ_), 192, 0, stream>>>(qraw, ref, vws, mid);
    out_gemm<<<dim3(256, 2), 256, 0, stream>>>(mid, wT + WOUTT_OFF, bout, out);
}